// Round 5
// baseline (1096.890 us; speedup 1.0000x reference)
//
#include <hip/hip_runtime.h>
#include <hip/hip_bf16.h>
#include <math.h>

typedef __hip_bfloat16 bf16;
typedef __hip_bfloat162 bf162;

#define N_NODES 100000
#define HID 128
#define NEG 0.2f

__device__ __forceinline__ float b2f(bf16 x) { return __bfloat162float(x); }
__device__ __forceinline__ bf16 f2b(float x) { return __float2bfloat16(x); }

// ---------------- CSR build ----------------

__global__ void k_zero_int(int* p, int n) {
    int i = blockIdx.x * blockDim.x + threadIdx.x;
    if (i < n) p[i] = 0;
}

__global__ void k_count(const int* __restrict__ ei, int E, int* __restrict__ deg) {
    int i = blockIdx.x * blockDim.x + threadIdx.x;
    if (i < E) {
        int u = ei[i], v = ei[E + i];
        atomicAdd(&deg[v], 1);
        atomicAdd(&deg[u], 1);
    } else if (i < E + N_NODES) {
        atomicAdd(&deg[i - E], 1);  // self loop
    }
}

// single-block exclusive scan over n ints (1024 threads, chunked Hillis + carry)
__global__ void k_scan1(const int* __restrict__ deg, int* __restrict__ rowptr,
                        int* __restrict__ rownext, int n) {
    __shared__ int buf[1024];
    __shared__ int carry;
    int t = threadIdx.x;
    if (t == 0) carry = 0;
    __syncthreads();
    for (int base = 0; base < n; base += 1024) {
        int i = base + t;
        int v = (i < n) ? deg[i] : 0;
        buf[t] = v;
        __syncthreads();
        for (int off = 1; off < 1024; off <<= 1) {
            int x = buf[t];
            int y = (t >= off) ? buf[t - off] : 0;
            __syncthreads();
            buf[t] = x + y;
            __syncthreads();
        }
        int incl = buf[t];
        int excl = incl - v;
        if (i < n) {
            int val = carry + excl;
            rowptr[i] = val;
            rownext[i] = val;
        }
        __syncthreads();                 // all carry reads done
        if (t == 1023) carry += buf[1023];
        __syncthreads();                 // carry update visible next chunk
    }
    if (t == 0) rowptr[n] = carry;
}

__global__ void k_fill(const int* __restrict__ ei, int E, int* __restrict__ rownext,
                       int* __restrict__ col) {
    int i = blockIdx.x * blockDim.x + threadIdx.x;
    if (i < E) {
        int u = ei[i], v = ei[E + i];
        col[atomicAdd(&rownext[v], 1)] = u;
        col[atomicAdd(&rownext[u], 1)] = v;
    } else if (i < E + N_NODES) {
        int d = i - E;
        col[atomicAdd(&rownext[d], 1)] = d;
    }
}

// ---------------- Layer 0 feature: z = x @ W0 (one wave per node) ----------------
// x: fp32 [n, indim], W: fp32 [indim, 128]. Lanes = output channels.

__global__ void k_feat0(const float* __restrict__ x, const float* __restrict__ W,
                        bf16* __restrict__ z, int n, int indim) {
    int wid = (int)((blockIdx.x * (size_t)blockDim.x + threadIdx.x) >> 6);
    int lane = threadIdx.x & 63;
    if (wid >= n) return;
    const float* xr = x + (size_t)wid * indim;
    float a0 = 0.f, a1 = 0.f;
    for (int k = 0; k < indim; k++) {
        float xv = xr[k];
        a0 += xv * W[k * HID + lane];
        a1 += xv * W[k * HID + lane + 64];
    }
    z[(size_t)wid * HID + lane] = f2b(a0);
    z[(size_t)wid * HID + lane + 64] = f2b(a1);
}

// ---------------- Layer 1 feature: z = h @ W1 (register-tiled) ----------------

__global__ void k_feat1(const bf16* __restrict__ h, const float* __restrict__ W,
                        bf16* __restrict__ z, int n) {
    __shared__ float tile[16][HID];
    int c = threadIdx.x;
    int n0 = blockIdx.x * 16;
    for (int r = 0; r < 16; r++) {
        int node = n0 + r;
        tile[r][c] = (node < n) ? b2f(h[(size_t)node * HID + c]) : 0.f;
    }
    __syncthreads();
    float acc[16];
#pragma unroll
    for (int r = 0; r < 16; r++) acc[r] = 0.f;
    for (int k = 0; k < HID; k++) {
        float w = W[k * HID + c];
#pragma unroll
        for (int r = 0; r < 16; r++) acc[r] += tile[r][k] * w;
    }
    for (int r = 0; r < 16; r++) {
        int node = n0 + r;
        if (node < n) z[(size_t)node * HID + c] = f2b(acc[r]);
    }
}

// ---------------- es/ed from z (one wave per node; lane = channel pair) ----------------

__global__ void k_attvec(const bf16* __restrict__ z, const float* __restrict__ as_,
                         const float* __restrict__ ad_, float* __restrict__ es,
                         float* __restrict__ ed, int n) {
    int wid = (int)((blockIdx.x * (size_t)blockDim.x + threadIdx.x) >> 6);
    int lane = threadIdx.x & 63;
    if (wid >= n) return;
    const bf162* zr = (const bf162*)z + (size_t)wid * 64;
    bf162 v = zr[lane];
    float2 a1 = ((const float2*)as_)[lane];
    float2 a2 = ((const float2*)ad_)[lane];
    float z0 = b2f(v.x), z1 = b2f(v.y);
    float ps = z0 * a1.x + z1 * a1.y;
    float pd = z0 * a2.x + z1 * a2.y;
    for (int off = 32; off > 0; off >>= 1) {
        ps += __shfl_down(ps, off);
        pd += __shfl_down(pd, off);
    }
    if (lane == 0) { es[wid] = ps; ed[wid] = pd; }
}

// ---------------- Attention aggregation (one wave per dst node) ----------------
// out[d,:] = elu( (sum_e p_e * z[src_e,:]) / (sum_e p_e) + bias ),  p_e = exp(leaky(es[s]+ed[d]) - max)

__global__ void k_agg(const bf16* __restrict__ z, const int* __restrict__ rowptr,
                      const int* __restrict__ col, const float* __restrict__ es,
                      const float* __restrict__ ed, const float* __restrict__ bias,
                      bf16* __restrict__ hout, int n) {
    int wid = (int)((blockIdx.x * (size_t)blockDim.x + threadIdx.x) >> 6);
    int lane = threadIdx.x & 63;
    if (wid >= n) return;
    int d = wid;
    int s0 = rowptr[d], s1 = rowptr[d + 1];
    float edv = ed[d];
    // pass A: max over leaky-relu'd logits (edges split across lanes)
    float m = -1e30f;
    for (int e = s0 + lane; e < s1; e += 64) {
        float a = es[col[e]] + edv;
        a = a > 0.f ? a : NEG * a;
        m = fmaxf(m, a);
    }
    for (int off = 32; off > 0; off >>= 1) m = fmaxf(m, __shfl_xor(m, off));
    // pass B: all lanes walk all edges; lane = channel pair (coalesced bf162)
    const bf162* zb = (const bf162*)z;
    float den = 0.f, acc0 = 0.f, acc1 = 0.f;
    for (int e = s0; e < s1; e++) {
        int s = col[e];
        float a = es[s] + edv;
        a = a > 0.f ? a : NEG * a;
        float p = __expf(a - m);
        den += p;
        bf162 v = zb[(size_t)s * 64 + lane];
        acc0 += p * b2f(v.x);
        acc1 += p * b2f(v.y);
    }
    float inv = 1.f / den;
    float2 bb = ((const float2*)bias)[lane];
    float o0 = acc0 * inv + bb.x;
    float o1 = acc1 * inv + bb.y;
    o0 = o0 > 0.f ? o0 : expm1f(o0);
    o1 = o1 > 0.f ? o1 : expm1f(o1);
    bf162 ov;
    ov.x = f2b(o0);
    ov.y = f2b(o1);
    ((bf162*)hout)[(size_t)d * 64 + lane] = ov;
}

// ---------------- Fused actor MLP + softmax: one wave per group of 16 candidates ----------------

__global__ void k_group(const bf16* __restrict__ h, const int* __restrict__ cand,
                        const float* __restrict__ mW0, const float* __restrict__ mb0,
                        const float* __restrict__ mW1, const float* __restrict__ mb1,
                        float* __restrict__ out) {
    __shared__ float tile[16][HID];
    __shared__ float sc[16];
    int lane = threadIdx.x;       // 0..63 (one wave)
    int g = blockIdx.x;
    for (int idx = lane; idx < 16 * HID; idx += 64) {
        int r = idx >> 7, c = idx & 127;
        tile[r][c] = b2f(h[(size_t)cand[g * 16 + r] * HID + c]);
    }
    __syncthreads();
    float w1a = mW1[lane], w1b = mW1[lane + 64];
    float b0a = mb0[lane], b0b = mb0[lane + 64];
    for (int r = 0; r < 16; r++) {
        float aa = 0.f, ab = 0.f;
        for (int k = 0; k < HID; k++) {
            float hv = tile[r][k];
            aa += hv * mW0[k * HID + lane];
            ab += hv * mW0[k * HID + lane + 64];
        }
        aa += b0a; ab += b0b;
        aa = fmaxf(aa, 0.f) * w1a;
        ab = fmaxf(ab, 0.f) * w1b;
        float s = aa + ab;
        for (int off = 32; off > 0; off >>= 1) s += __shfl_down(s, off);
        if (lane == 0) sc[r] = s + mb1[0];
    }
    __syncthreads();
    if (lane == 0) {
        float m = -1e30f;
        for (int j = 0; j < 16; j++) m = fmaxf(m, sc[j]);
        float e[16], den = 0.f;
        for (int j = 0; j < 16; j++) { e[j] = __expf(sc[j] - m); den += e[j]; }
        float inv = 1.f / den;
        for (int j = 0; j < 16; j++) out[g * 16 + j] = e[j] * inv;
    }
}

// ---------------- launch ----------------

extern "C" void kernel_launch(void* const* d_in, const int* in_sizes, int n_in,
                              void* d_out, int out_size, void* d_ws, size_t ws_size,
                              hipStream_t stream) {
    const int N = N_NODES;
    const float* state = (const float*)d_in[0];
    const int* ei   = (const int*)d_in[1];
    const int* cand = (const int*)d_in[2];
    const float* W0  = (const float*)d_in[3];
    const float* as0 = (const float*)d_in[4];
    const float* ad0 = (const float*)d_in[5];
    const float* b0  = (const float*)d_in[6];
    const float* W1  = (const float*)d_in[7];
    const float* as1 = (const float*)d_in[8];
    const float* ad1 = (const float*)d_in[9];
    const float* b1  = (const float*)d_in[10];
    const float* mW0 = (const float*)d_in[11];
    const float* mb0 = (const float*)d_in[12];
    const float* mW1 = (const float*)d_in[13];
    const float* mb1 = (const float*)d_in[14];

    int E = in_sizes[1] / 2;
    int M = 2 * E + N;
    int indim = in_sizes[0] / N;
    int ncand = in_sizes[2];          // 65536
    int ngroups = ncand / 16;         // 4096

    // workspace layout (~60 MB)
    char* p = (char*)d_ws;
    bf16* zb = (bf16*)p;              p += (size_t)N * HID * 2;   // 25.6 MB
    bf16* hb = (bf16*)p;              p += (size_t)N * HID * 2;   // 25.6 MB
    float* es = (float*)p;            p += (size_t)N * 4;
    float* ed = (float*)p;            p += (size_t)N * 4;
    int* rowptr  = (int*)p;           p += (size_t)(N + 1) * 4;
    int* rownext = (int*)p;           p += (size_t)N * 4;
    int* col     = (int*)p;           p += (size_t)M * 4;         // 6.8 MB

    int nwb = (N + 3) / 4;  // blocks for one-wave-per-node kernels (256 thr)

    // ---- CSR build (deg accumulated in rownext) ----
    k_zero_int<<<(N + 255) / 256, 256, 0, stream>>>(rownext, N);
    k_count<<<(E + N + 255) / 256, 256, 0, stream>>>(ei, E, rownext);
    k_scan1<<<1, 1024, 0, stream>>>(rownext, rowptr, rownext, N);
    k_fill<<<(E + N + 255) / 256, 256, 0, stream>>>(ei, E, rownext, col);

    // ---- GAT layer 0 ----
    k_feat0<<<nwb, 256, 0, stream>>>(state, W0, zb, N, indim);
    k_attvec<<<nwb, 256, 0, stream>>>(zb, as0, ad0, es, ed, N);
    k_agg<<<nwb, 256, 0, stream>>>(zb, rowptr, col, es, ed, b0, hb, N);

    // ---- GAT layer 1 ----
    k_feat1<<<(N + 15) / 16, HID, 0, stream>>>(hb, W1, zb, N);
    k_attvec<<<nwb, 256, 0, stream>>>(zb, as1, ad1, es, ed, N);
    k_agg<<<nwb, 256, 0, stream>>>(zb, rowptr, col, es, ed, b1, hb, N);

    // ---- fused actor MLP + softmax (writes d_out directly) ----
    k_group<<<ngroups, 64, 0, stream>>>(hb, cand, mW0, mb0, mW1, mb1, (float*)d_out);
}

// Round 6
// 765.677 us; speedup vs baseline: 1.4326x; 1.4326x over previous
//
#include <hip/hip_runtime.h>
#include <hip/hip_bf16.h>
#include <math.h>

typedef __hip_bfloat16 bf16;
typedef __hip_bfloat162 bf162;

#define N_NODES 100000
#define HID 128
#define NEG 0.2f

__device__ __forceinline__ float b2f(bf16 x) { return __bfloat162float(x); }
__device__ __forceinline__ bf16 f2b(float x) { return __float2bfloat16(x); }
__device__ __forceinline__ float lo_bf(unsigned int u) {
    union { unsigned int i; float f; } c; c.i = u << 16; return c.f;
}
__device__ __forceinline__ float hi_bf(unsigned int u) {
    union { unsigned int i; float f; } c; c.i = u & 0xffff0000u; return c.f;
}

// ---------------- CSR build ----------------

__global__ void k_zero_int(int* p, int n) {
    int i = blockIdx.x * blockDim.x + threadIdx.x;
    if (i < n) p[i] = 0;
}

__global__ void k_count(const int* __restrict__ ei, int E, int* __restrict__ deg) {
    int i = blockIdx.x * blockDim.x + threadIdx.x;
    if (i < E) {
        int u = ei[i], v = ei[E + i];
        atomicAdd(&deg[v], 1);
        atomicAdd(&deg[u], 1);
    } else if (i < E + N_NODES) {
        atomicAdd(&deg[i - E], 1);  // self loop
    }
}

// multi-block scan: per-1024-chunk sums -> serial exclusive over chunk sums -> in-chunk scan
__global__ void k_scan_sum(const int* __restrict__ deg, int* __restrict__ partials, int n) {
    __shared__ int red[256];
    int base = blockIdx.x * 1024;
    int t = threadIdx.x;
    int s = 0;
    for (int j = t; j < 1024; j += 256) {
        int i = base + j;
        s += (i < n) ? deg[i] : 0;
    }
    red[t] = s;
    __syncthreads();
    for (int off = 128; off > 0; off >>= 1) {
        if (t < off) red[t] += red[t + off];
        __syncthreads();
    }
    if (t == 0) partials[blockIdx.x] = red[0];
}

__global__ void k_scan_part(int* __restrict__ partials, int nb, int* __restrict__ rowptr, int n) {
    if (threadIdx.x == 0 && blockIdx.x == 0) {
        int acc = 0;
        for (int b = 0; b < nb; b++) {
            int v = partials[b];
            partials[b] = acc;
            acc += v;
        }
        rowptr[n] = acc;
    }
}

__global__ void k_scan_final(const int* __restrict__ deg, const int* __restrict__ partials,
                             int* __restrict__ rowptr, int* __restrict__ rownext, int n) {
    __shared__ int buf[2][1024];
    int t = threadIdx.x;
    int i = blockIdx.x * 1024 + t;
    int v = (i < n) ? deg[i] : 0;
    buf[0][t] = v;
    __syncthreads();
    int cur = 0;
    for (int off = 1; off < 1024; off <<= 1) {
        int x = buf[cur][t];
        if (t >= off) x += buf[cur][t - off];
        buf[cur ^ 1][t] = x;
        cur ^= 1;
        __syncthreads();
    }
    if (i < n) {
        int ex = partials[blockIdx.x] + buf[cur][t] - v;  // exclusive
        rowptr[i] = ex;
        rownext[i] = ex;
    }
}

__global__ void k_fill(const int* __restrict__ ei, int E, int* __restrict__ rownext,
                       int* __restrict__ col) {
    int i = blockIdx.x * blockDim.x + threadIdx.x;
    if (i < E) {
        int u = ei[i], v = ei[E + i];
        col[atomicAdd(&rownext[v], 1)] = u;
        col[atomicAdd(&rownext[u], 1)] = v;
    } else if (i < E + N_NODES) {
        int d = i - E;
        col[atomicAdd(&rownext[d], 1)] = d;
    }
}

// ---------------- Layer 0: z = x @ W0 + fused es/ed (one wave per node) ----------------

__global__ void k_feat0(const float* __restrict__ x, const float* __restrict__ W,
                        const float* __restrict__ as_, const float* __restrict__ ad_,
                        bf16* __restrict__ z, float* __restrict__ es, float* __restrict__ ed,
                        int n, int indim) {
    int wid = (int)((blockIdx.x * (size_t)blockDim.x + threadIdx.x) >> 6);
    int lane = threadIdx.x & 63;
    if (wid >= n) return;
    const float* xr = x + (size_t)wid * indim;
    float a0 = 0.f, a1 = 0.f;
    for (int k = 0; k < indim; k++) {
        float xv = xr[k];               // wave-uniform
        a0 += xv * W[k * HID + lane];
        a1 += xv * W[k * HID + lane + 64];
    }
    z[(size_t)wid * HID + lane] = f2b(a0);
    z[(size_t)wid * HID + lane + 64] = f2b(a1);
    float ps = a0 * as_[lane] + a1 * as_[lane + 64];
    float pd = a0 * ad_[lane] + a1 * ad_[lane + 64];
#pragma unroll
    for (int off = 32; off > 0; off >>= 1) {
        ps += __shfl_down(ps, off);
        pd += __shfl_down(pd, off);
    }
    if (lane == 0) { es[wid] = ps; ed[wid] = pd; }
}

// ---------------- Layer 1 feature: z = h @ W1 (register-tiled, float4 LDS reads) ----------------
// N % 16 == 0 (100000 = 6250 * 16) -> no tail guards needed.

__global__ void k_feat1(const bf16* __restrict__ h, const float* __restrict__ W,
                        bf16* __restrict__ z, int n) {
    __shared__ float tile[16][HID];   // 8 KB
    int c = threadIdx.x;              // 0..127
    int n0 = blockIdx.x * 16;
    const uint4* hv = (const uint4*)(h + (size_t)n0 * HID);  // 16 rows * 16 uint4
#pragma unroll
    for (int q = c; q < 256; q += 128) {
        uint4 raw = hv[q];
        int r = q >> 4, t = q & 15;
        float* dst = &tile[r][t * 8];
        dst[0] = lo_bf(raw.x); dst[1] = hi_bf(raw.x);
        dst[2] = lo_bf(raw.y); dst[3] = hi_bf(raw.y);
        dst[4] = lo_bf(raw.z); dst[5] = hi_bf(raw.z);
        dst[6] = lo_bf(raw.w); dst[7] = hi_bf(raw.w);
    }
    __syncthreads();
    float acc[16];
#pragma unroll
    for (int r = 0; r < 16; r++) acc[r] = 0.f;
    for (int k4 = 0; k4 < HID / 4; k4++) {
        int k = k4 * 4;
        float w0 = W[(k + 0) * HID + c];
        float w1 = W[(k + 1) * HID + c];
        float w2 = W[(k + 2) * HID + c];
        float w3 = W[(k + 3) * HID + c];
#pragma unroll
        for (int r = 0; r < 16; r++) {
            float4 h4 = *(const float4*)&tile[r][k];
            acc[r] += h4.x * w0 + h4.y * w1 + h4.z * w2 + h4.w * w3;
        }
    }
#pragma unroll
    for (int r = 0; r < 16; r++) z[(size_t)(n0 + r) * HID + c] = f2b(acc[r]);
}

// ---------------- es/ed from z (one wave per node; lane = channel pair) ----------------

__global__ void k_attvec(const bf16* __restrict__ z, const float* __restrict__ as_,
                         const float* __restrict__ ad_, float* __restrict__ es,
                         float* __restrict__ ed, int n) {
    int wid = (int)((blockIdx.x * (size_t)blockDim.x + threadIdx.x) >> 6);
    int lane = threadIdx.x & 63;
    if (wid >= n) return;
    const bf162* zr = (const bf162*)z + (size_t)wid * 64;
    bf162 v = zr[lane];
    float2 a1 = ((const float2*)as_)[lane];
    float2 a2 = ((const float2*)ad_)[lane];
    float z0 = b2f(v.x), z1 = b2f(v.y);
    float ps = z0 * a1.x + z1 * a1.y;
    float pd = z0 * a2.x + z1 * a2.y;
#pragma unroll
    for (int off = 32; off > 0; off >>= 1) {
        ps += __shfl_down(ps, off);
        pd += __shfl_down(pd, off);
    }
    if (lane == 0) { es[wid] = ps; ed[wid] = pd; }
}

// ---------------- Attention aggregation (one wave per dst; 4 edges x 16 lanes per iter) ----------------
// out[d,:] = elu( (sum_e p_e * z[src_e,:]) / (sum_e p_e) + bias ),  p_e = exp(leaky(es[s]+ed[d]) - max)

__global__ void k_agg(const bf16* __restrict__ z, const int* __restrict__ rowptr,
                      const int* __restrict__ col, const float* __restrict__ es,
                      const float* __restrict__ ed, const float* __restrict__ bias,
                      bf16* __restrict__ hout, int n) {
    int wid = (int)((blockIdx.x * (size_t)blockDim.x + threadIdx.x) >> 6);
    int lane = threadIdx.x & 63;
    if (wid >= n) return;
    int d = wid;
    int s0 = rowptr[d], s1 = rowptr[d + 1];
    float edv = ed[d];
    // pass A: max over leaky-relu'd logits
    float m = -1e30f;
    for (int e = s0 + lane; e < s1; e += 64) {
        float a = es[col[e]] + edv;
        a = a > 0.f ? a : NEG * a;
        m = fmaxf(m, a);
    }
#pragma unroll
    for (int off = 32; off > 0; off >>= 1) m = fmaxf(m, __shfl_xor(m, off));
    // pass B: lane = (g,t); edge slot g in [0,4), channel quad t in [0,16)
    int g = lane >> 4, t = lane & 15;
    const uint4* zr = (const uint4*)z;   // row = 16 uint4 (128 bf16)
    float acc[8];
#pragma unroll
    for (int j = 0; j < 8; j++) acc[j] = 0.f;
    float den = 0.f;
    for (int e0 = s0; e0 < s1; e0 += 4) {
        int e = e0 + g;
        bool ok = (e < s1);
        int s = col[ok ? e : s1 - 1];
        float a = es[s] + edv;
        a = a > 0.f ? a : NEG * a;
        float p = ok ? __expf(a - m) : 0.f;
        den += p;
        uint4 raw = zr[(size_t)s * 16 + t];
        acc[0] += p * lo_bf(raw.x); acc[1] += p * hi_bf(raw.x);
        acc[2] += p * lo_bf(raw.y); acc[3] += p * hi_bf(raw.y);
        acc[4] += p * lo_bf(raw.z); acc[5] += p * hi_bf(raw.z);
        acc[6] += p * lo_bf(raw.w); acc[7] += p * hi_bf(raw.w);
    }
    // combine the 4 edge-slot groups
#pragma unroll
    for (int off = 16; off <= 32; off <<= 1) {
        den += __shfl_xor(den, off);
#pragma unroll
        for (int j = 0; j < 8; j++) acc[j] += __shfl_xor(acc[j], off);
    }
    if (g == 0) {
        float inv = 1.f / den;
        union { bf16 hv[8]; uint4 v; } uo;
#pragma unroll
        for (int j = 0; j < 8; j++) {
            float o = acc[j] * inv + bias[t * 8 + j];
            o = o > 0.f ? o : expm1f(o);
            uo.hv[j] = f2b(o);
        }
        ((uint4*)hout)[(size_t)d * 16 + t] = uo.v;
    }
}

// ---------------- Fused actor MLP + softmax: one wave per group of 16 candidates ----------------

__global__ void k_group(const bf16* __restrict__ h, const int* __restrict__ cand,
                        const float* __restrict__ mW0, const float* __restrict__ mb0,
                        const float* __restrict__ mW1, const float* __restrict__ mb1,
                        float* __restrict__ out) {
    __shared__ float tile[16][HID];
    __shared__ int cidx[16];
    __shared__ float sc[16];
    int lane = threadIdx.x;       // 0..63 (one wave)
    int g = blockIdx.x;
    if (lane < 16) cidx[lane] = cand[g * 16 + lane];
    __syncthreads();
#pragma unroll
    for (int q = lane; q < 256; q += 64) {
        int r = q >> 4, t = q & 15;
        uint4 raw = ((const uint4*)(h + (size_t)cidx[r] * HID))[t];
        float* dst = &tile[r][t * 8];
        dst[0] = lo_bf(raw.x); dst[1] = hi_bf(raw.x);
        dst[2] = lo_bf(raw.y); dst[3] = hi_bf(raw.y);
        dst[4] = lo_bf(raw.z); dst[5] = hi_bf(raw.z);
        dst[6] = lo_bf(raw.w); dst[7] = hi_bf(raw.w);
    }
    __syncthreads();
    float acc0[16], acc1[16];
#pragma unroll
    for (int r = 0; r < 16; r++) { acc0[r] = 0.f; acc1[r] = 0.f; }
    for (int k4 = 0; k4 < HID / 4; k4++) {
        int k = k4 * 4;
        float wa0 = mW0[(k + 0) * HID + lane], wb0 = mW0[(k + 0) * HID + lane + 64];
        float wa1 = mW0[(k + 1) * HID + lane], wb1 = mW0[(k + 1) * HID + lane + 64];
        float wa2 = mW0[(k + 2) * HID + lane], wb2 = mW0[(k + 2) * HID + lane + 64];
        float wa3 = mW0[(k + 3) * HID + lane], wb3 = mW0[(k + 3) * HID + lane + 64];
#pragma unroll
        for (int r = 0; r < 16; r++) {
            float4 h4 = *(const float4*)&tile[r][k];
            acc0[r] += h4.x * wa0 + h4.y * wa1 + h4.z * wa2 + h4.w * wa3;
            acc1[r] += h4.x * wb0 + h4.y * wb1 + h4.z * wb2 + h4.w * wb3;
        }
    }
    float w1a = mW1[lane], w1b = mW1[lane + 64];
    float b0a = mb0[lane], b0b = mb0[lane + 64];
    float bias1 = mb1[0];
#pragma unroll
    for (int r = 0; r < 16; r++) {
        float s = fmaxf(acc0[r] + b0a, 0.f) * w1a + fmaxf(acc1[r] + b0b, 0.f) * w1b;
#pragma unroll
        for (int off = 32; off > 0; off >>= 1) s += __shfl_down(s, off);
        if (lane == 0) sc[r] = s + bias1;
    }
    __syncthreads();
    if (lane == 0) {
        float m = -1e30f;
#pragma unroll
        for (int j = 0; j < 16; j++) m = fmaxf(m, sc[j]);
        float e[16], den = 0.f;
#pragma unroll
        for (int j = 0; j < 16; j++) { e[j] = __expf(sc[j] - m); den += e[j]; }
        float inv = 1.f / den;
#pragma unroll
        for (int j = 0; j < 16; j++) out[g * 16 + j] = e[j] * inv;
    }
}

// ---------------- launch ----------------

extern "C" void kernel_launch(void* const* d_in, const int* in_sizes, int n_in,
                              void* d_out, int out_size, void* d_ws, size_t ws_size,
                              hipStream_t stream) {
    const int N = N_NODES;
    const float* state = (const float*)d_in[0];
    const int* ei   = (const int*)d_in[1];
    const int* cand = (const int*)d_in[2];
    const float* W0  = (const float*)d_in[3];
    const float* as0 = (const float*)d_in[4];
    const float* ad0 = (const float*)d_in[5];
    const float* b0  = (const float*)d_in[6];
    const float* W1  = (const float*)d_in[7];
    const float* as1 = (const float*)d_in[8];
    const float* ad1 = (const float*)d_in[9];
    const float* b1  = (const float*)d_in[10];
    const float* mW0 = (const float*)d_in[11];
    const float* mb0 = (const float*)d_in[12];
    const float* mW1 = (const float*)d_in[13];
    const float* mb1 = (const float*)d_in[14];

    int E = in_sizes[1] / 2;
    int M = 2 * E + N;
    int indim = in_sizes[0] / N;
    int ncand = in_sizes[2];          // 65536
    int ngroups = ncand / 16;         // 4096

    // workspace layout (~60 MB)
    char* p = (char*)d_ws;
    bf16* zb = (bf16*)p;              p += (size_t)N * HID * 2;   // 25.6 MB
    bf16* hb = (bf16*)p;              p += (size_t)N * HID * 2;   // 25.6 MB
    float* es = (float*)p;            p += (size_t)N * 4;
    float* ed = (float*)p;            p += (size_t)N * 4;
    int* rowptr  = (int*)p;           p += (size_t)(N + 1) * 4;
    int* rownext = (int*)p;           p += (size_t)N * 4;
    int* col     = (int*)p;           p += (size_t)M * 4;         // 6.8 MB
    int* partials = (int*)p;          p += 512;

    int nwb = (N + 3) / 4;  // blocks for one-wave-per-node kernels (256 thr)
    int NB = (N + 1023) / 1024;

    // ---- CSR build (deg accumulated in rownext) ----
    k_zero_int<<<(N + 255) / 256, 256, 0, stream>>>(rownext, N);
    k_count<<<(E + N + 255) / 256, 256, 0, stream>>>(ei, E, rownext);
    k_scan_sum<<<NB, 256, 0, stream>>>(rownext, partials, N);
    k_scan_part<<<1, 64, 0, stream>>>(partials, NB, rowptr, N);
    k_scan_final<<<NB, 1024, 0, stream>>>(rownext, partials, rowptr, rownext, N);
    k_fill<<<(E + N + 255) / 256, 256, 0, stream>>>(ei, E, rownext, col);

    // ---- GAT layer 0 (es/ed fused into feature kernel) ----
    k_feat0<<<nwb, 256, 0, stream>>>(state, W0, as0, ad0, zb, es, ed, N, indim);
    k_agg<<<nwb, 256, 0, stream>>>(zb, rowptr, col, es, ed, b0, hb, N);

    // ---- GAT layer 1 ----
    k_feat1<<<N / 16, HID, 0, stream>>>(hb, W1, zb, N);
    k_attvec<<<nwb, 256, 0, stream>>>(zb, as1, ad1, es, ed, N);
    k_agg<<<nwb, 256, 0, stream>>>(zb, rowptr, col, es, ed, b1, hb, N);

    // ---- fused actor MLP + softmax (writes d_out directly) ----
    k_group<<<ngroups, 64, 0, stream>>>(hb, cand, mW0, mb0, mW1, mb1, (float*)d_out);
}

// Round 7
// 562.343 us; speedup vs baseline: 1.9506x; 1.3616x over previous
//
#include <hip/hip_runtime.h>
#include <hip/hip_bf16.h>
#include <math.h>

typedef __hip_bfloat16 bf16;

#define N_NODES 100000
#define HID 128
#define NEG 0.2f
#define NBUCK 256
#define BSHIFT 9          // 512 nodes per bucket; 256*512 = 131072 >= N
#define ECAP 96           // per-wave LDS edge cache (mean deg 16, Poisson tail << 96)

__device__ __forceinline__ float b2f(bf16 x) { return __bfloat162float(x); }
__device__ __forceinline__ bf16 f2b(float x) { return __float2bfloat16(x); }
__device__ __forceinline__ float lo_bf(unsigned int u) {
    union { unsigned int i; float f; } c; c.i = u << 16; return c.f;
}
__device__ __forceinline__ float hi_bf(unsigned int u) {
    union { unsigned int i; float f; } c; c.i = u & 0xffff0000u; return c.f;
}

// ---------------- CSR build: bucketed counting sort ----------------

__global__ void k_zero_int(int* p, int n) {
    int i = blockIdx.x * blockDim.x + threadIdx.x;
    if (i < n) p[i] = 0;
}

// pass 1: bucket histogram (both edge directions; self-loops handled inline in k_agg)
__global__ void k_bhist(const int* __restrict__ ei, int E, int* __restrict__ bcnt) {
    __shared__ int h[NBUCK];
    int t = threadIdx.x;
    h[t] = 0;
    __syncthreads();
    int i = blockIdx.x * blockDim.x + t;
    int stride = gridDim.x * blockDim.x;
    for (; i < E; i += stride) {
        int u = ei[i], v = ei[E + i];
        atomicAdd(&h[v >> BSHIFT], 1);
        atomicAdd(&h[u >> BSHIFT], 1);
    }
    __syncthreads();
    if (h[t]) atomicAdd(&bcnt[t], h[t]);
}

// pass 2: exclusive scan of 256 bucket counts
__global__ void k_bscan(const int* __restrict__ bcnt, int* __restrict__ bbase,
                        int* __restrict__ bnext) {
    __shared__ int buf[2][NBUCK];
    int t = threadIdx.x;
    int v = bcnt[t];
    buf[0][t] = v;
    __syncthreads();
    int cur = 0;
    for (int off = 1; off < NBUCK; off <<= 1) {
        int x = buf[cur][t] + ((t >= off) ? buf[cur][t - off] : 0);
        buf[cur ^ 1][t] = x;
        cur ^= 1;
        __syncthreads();
    }
    int incl = buf[cur][t];
    int excl = incl - v;
    bbase[t] = excl;
    bnext[t] = excl;
    if (t == NBUCK - 1) bbase[NBUCK] = incl;
}

// pass 3: scatter (dst,src) pairs into bucket regions with per-block reservation
#define SCH 2048
#define SK 8
__global__ __launch_bounds__(256) void k_bscatter(const int* __restrict__ ei, int E,
                                                  int* __restrict__ bnext,
                                                  int2* __restrict__ pairs) {
    __shared__ int h[NBUCK], base[NBUCK], h2[NBUCK];
    int t = threadIdx.x;
    h[t] = 0; h2[t] = 0;
    __syncthreads();
    int b0 = blockIdx.x * SCH;
    int eu[SK], ev[SK];
#pragma unroll
    for (int k = 0; k < SK; k++) {
        int i = b0 + k * 256 + t;
        if (i < E) {
            int u = ei[i], v = ei[E + i];
            eu[k] = u; ev[k] = v;
            atomicAdd(&h[v >> BSHIFT], 1);
            atomicAdd(&h[u >> BSHIFT], 1);
        } else { eu[k] = -1; ev[k] = -1; }
    }
    __syncthreads();
    if (h[t] > 0) base[t] = atomicAdd(&bnext[t], h[t]);
    __syncthreads();
#pragma unroll
    for (int k = 0; k < SK; k++) {
        if (eu[k] >= 0) {
            int u = eu[k], v = ev[k];
            int bv = v >> BSHIFT;
            pairs[base[bv] + atomicAdd(&h2[bv], 1)] = make_int2(v, u);
            int bu = u >> BSHIFT;
            pairs[base[bu] + atomicAdd(&h2[bu], 1)] = make_int2(u, v);
        }
    }
}

// pass 4: per-bucket counting sort -> rowptr + col
__global__ __launch_bounds__(256) void k_bbuild(const int2* __restrict__ pairs,
                                                const int* __restrict__ bbase,
                                                int* __restrict__ rowptr,
                                                int* __restrict__ col, int n) {
    __shared__ int deg[512];
    __shared__ int off[512];
    __shared__ int s2[2][256];
    int t = threadIdx.x;
    int b = blockIdx.x;
    int node0 = b << BSHIFT;
    deg[t] = 0; deg[t + 256] = 0;
    __syncthreads();
    int p0 = bbase[b], p1 = bbase[b + 1];
    for (int i = p0 + t; i < p1; i += 256) atomicAdd(&deg[pairs[i].x - node0], 1);
    __syncthreads();
    int a0 = deg[2 * t], a1 = deg[2 * t + 1];
    int s = a0 + a1;
    s2[0][t] = s;
    __syncthreads();
    int cur = 0;
    for (int o = 1; o < 256; o <<= 1) {
        int x = s2[cur][t] + ((t >= o) ? s2[cur][t - o] : 0);
        s2[cur ^ 1][t] = x;
        cur ^= 1;
        __syncthreads();
    }
    int excl = s2[cur][t] - s;
    off[2 * t] = excl;
    off[2 * t + 1] = excl + a0;
    __syncthreads();
    // rowptr (coalesced); node==n written exactly once (bucket 195, j=160)
    for (int j = t; j < 512; j += 256) {
        int node = node0 + j;
        if (node <= n) rowptr[node] = p0 + off[j];
    }
    // reset deg as placement counters
    deg[t] = 0; deg[t + 256] = 0;
    __syncthreads();
    for (int i = p0 + t; i < p1; i += 256) {
        int2 pr = pairs[i];
        int d = pr.x - node0;
        int ofs = atomicAdd(&deg[d], 1);
        col[p0 + off[d] + ofs] = pr.y;
    }
}

// ---------------- Layer 0: z = x @ W0 + fused es/ed (one wave per node) ----------------

__global__ void k_feat0(const float* __restrict__ x, const float* __restrict__ W,
                        const float* __restrict__ as_, const float* __restrict__ ad_,
                        bf16* __restrict__ z, float* __restrict__ es, float* __restrict__ ed,
                        int n, int indim) {
    int wid = (int)((blockIdx.x * (size_t)blockDim.x + threadIdx.x) >> 6);
    int lane = threadIdx.x & 63;
    if (wid >= n) return;
    const float* xr = x + (size_t)wid * indim;
    float a0 = 0.f, a1 = 0.f;
    for (int k = 0; k < indim; k++) {
        float xv = xr[k];               // wave-uniform
        a0 += xv * W[k * HID + lane];
        a1 += xv * W[k * HID + lane + 64];
    }
    z[(size_t)wid * HID + lane] = f2b(a0);
    z[(size_t)wid * HID + lane + 64] = f2b(a1);
    float ps = a0 * as_[lane] + a1 * as_[lane + 64];
    float pd = a0 * ad_[lane] + a1 * ad_[lane + 64];
#pragma unroll
    for (int off = 32; off > 0; off >>= 1) {
        ps += __shfl_down(ps, off);
        pd += __shfl_down(pd, off);
    }
    if (lane == 0) { es[wid] = ps; ed[wid] = pd; }
}

// ---------------- Layer 1 feature: z = h @ W1 (register-tiled, float4 LDS reads) ----------------

__global__ void k_feat1(const bf16* __restrict__ h, const float* __restrict__ W,
                        bf16* __restrict__ z, int n) {
    __shared__ float tile[16][HID];   // 8 KB
    int c = threadIdx.x;              // 0..127
    int n0 = blockIdx.x * 16;
    const uint4* hv = (const uint4*)(h + (size_t)n0 * HID);
#pragma unroll
    for (int q = c; q < 256; q += 128) {
        uint4 raw = hv[q];
        int r = q >> 4, t = q & 15;
        float* dst = &tile[r][t * 8];
        dst[0] = lo_bf(raw.x); dst[1] = hi_bf(raw.x);
        dst[2] = lo_bf(raw.y); dst[3] = hi_bf(raw.y);
        dst[4] = lo_bf(raw.z); dst[5] = hi_bf(raw.z);
        dst[6] = lo_bf(raw.w); dst[7] = hi_bf(raw.w);
    }
    __syncthreads();
    float acc[16];
#pragma unroll
    for (int r = 0; r < 16; r++) acc[r] = 0.f;
    for (int k4 = 0; k4 < HID / 4; k4++) {
        int k = k4 * 4;
        float w0 = W[(k + 0) * HID + c];
        float w1 = W[(k + 1) * HID + c];
        float w2 = W[(k + 2) * HID + c];
        float w3 = W[(k + 3) * HID + c];
#pragma unroll
        for (int r = 0; r < 16; r++) {
            float4 h4 = *(const float4*)&tile[r][k];
            acc[r] += h4.x * w0 + h4.y * w1 + h4.z * w2 + h4.w * w3;
        }
    }
#pragma unroll
    for (int r = 0; r < 16; r++) z[(size_t)(n0 + r) * HID + c] = f2b(acc[r]);
}

// ---------------- es/ed from z (one wave per node; lane = channel pair) ----------------

__global__ void k_attvec(const bf16* __restrict__ z, const float* __restrict__ as_,
                         const float* __restrict__ ad_, float* __restrict__ es,
                         float* __restrict__ ed, int n) {
    int wid = (int)((blockIdx.x * (size_t)blockDim.x + threadIdx.x) >> 6);
    int lane = threadIdx.x & 63;
    if (wid >= n) return;
    const __hip_bfloat162* zr = (const __hip_bfloat162*)z + (size_t)wid * 64;
    __hip_bfloat162 v = zr[lane];
    float2 a1 = ((const float2*)as_)[lane];
    float2 a2 = ((const float2*)ad_)[lane];
    float z0 = b2f(v.x), z1 = b2f(v.y);
    float ps = z0 * a1.x + z1 * a1.y;
    float pd = z0 * a2.x + z1 * a2.y;
#pragma unroll
    for (int off = 32; off > 0; off >>= 1) {
        ps += __shfl_down(ps, off);
        pd += __shfl_down(pd, off);
    }
    if (lane == 0) { es[wid] = ps; ed[wid] = pd; }
}

// ---------------- Attention aggregation (one wave per dst; LDS logit cache; inline self-loop) ----------------

__global__ __launch_bounds__(256) void k_agg(const bf16* __restrict__ z,
                      const int* __restrict__ rowptr, const int* __restrict__ col,
                      const float* __restrict__ es, const float* __restrict__ ed,
                      const float* __restrict__ bias, bf16* __restrict__ hout, int n) {
    __shared__ float acache[4][ECAP];
    __shared__ int scache[4][ECAP];
    int wv = threadIdx.x >> 6;
    int lane = threadIdx.x & 63;
    int wid = blockIdx.x * 4 + wv;     // N % 4 == 0 -> all waves valid (barrier-safe)
    if (wid >= n) return;
    int d = wid;
    int s0 = rowptr[d], s1 = rowptr[d + 1];
    float edv = ed[d];
    float aself = es[d] + edv;
    aself = aself > 0.f ? aself : NEG * aself;
    // pass A: max over logits + cache (logit, src) per edge
    float m = aself;
    for (int e = s0 + lane; e < s1; e += 64) {
        int s = col[e];
        float a = es[s] + edv;
        a = a > 0.f ? a : NEG * a;
        int q = e - s0;
        if (q < ECAP) { acache[wv][q] = a; scache[wv][q] = s; }
        m = fmaxf(m, a);
    }
#pragma unroll
    for (int off = 32; off > 0; off >>= 1) m = fmaxf(m, __shfl_xor(m, off));
    __syncthreads();
    // pass B: lane = (g,t); edge slot g in [0,4), channel quad t in [0,16)
    int g = lane >> 4, t = lane & 15;
    const uint4* zr = (const uint4*)z;
    float acc[8];
#pragma unroll
    for (int j = 0; j < 8; j++) acc[j] = 0.f;
    float den = 0.f;
    for (int e0 = s0; e0 < s1; e0 += 4) {
        int e = e0 + g;
        bool ok = (e < s1);
        int ee = ok ? e : s1 - 1;
        int q = ee - s0;
        int s; float a;
        if (q < ECAP) { s = scache[wv][q]; a = acache[wv][q]; }
        else { s = col[ee]; a = es[s] + edv; a = a > 0.f ? a : NEG * a; }
        float p = ok ? __expf(a - m) : 0.f;
        den += p;
        uint4 raw = zr[(size_t)s * 16 + t];
        acc[0] += p * lo_bf(raw.x); acc[1] += p * hi_bf(raw.x);
        acc[2] += p * lo_bf(raw.y); acc[3] += p * hi_bf(raw.y);
        acc[4] += p * lo_bf(raw.z); acc[5] += p * hi_bf(raw.z);
        acc[6] += p * lo_bf(raw.w); acc[7] += p * hi_bf(raw.w);
    }
#pragma unroll
    for (int off = 16; off <= 32; off <<= 1) {
        den += __shfl_xor(den, off);
#pragma unroll
        for (int j = 0; j < 8; j++) acc[j] += __shfl_xor(acc[j], off);
    }
    if (g == 0) {
        // self-loop contribution (once)
        float pself = __expf(aself - m);
        den += pself;
        uint4 raw = zr[(size_t)d * 16 + t];
        acc[0] += pself * lo_bf(raw.x); acc[1] += pself * hi_bf(raw.x);
        acc[2] += pself * lo_bf(raw.y); acc[3] += pself * hi_bf(raw.y);
        acc[4] += pself * lo_bf(raw.z); acc[5] += pself * hi_bf(raw.z);
        acc[6] += pself * lo_bf(raw.w); acc[7] += pself * hi_bf(raw.w);
        float inv = 1.f / den;
        union { bf16 hv[8]; uint4 v; } uo;
#pragma unroll
        for (int j = 0; j < 8; j++) {
            float o = acc[j] * inv + bias[t * 8 + j];
            o = o > 0.f ? o : expm1f(o);
            uo.hv[j] = f2b(o);
        }
        ((uint4*)hout)[(size_t)d * 16 + t] = uo.v;
    }
}

// ---------------- Fused actor MLP + softmax: one wave per group of 16 candidates ----------------

__global__ void k_group(const bf16* __restrict__ h, const int* __restrict__ cand,
                        const float* __restrict__ mW0, const float* __restrict__ mb0,
                        const float* __restrict__ mW1, const float* __restrict__ mb1,
                        float* __restrict__ out) {
    __shared__ float tile[16][HID];
    __shared__ int cidx[16];
    __shared__ float sc[16];
    int lane = threadIdx.x;       // 0..63 (one wave)
    int g = blockIdx.x;
    if (lane < 16) cidx[lane] = cand[g * 16 + lane];
    __syncthreads();
#pragma unroll
    for (int q = lane; q < 256; q += 64) {
        int r = q >> 4, t = q & 15;
        uint4 raw = ((const uint4*)(h + (size_t)cidx[r] * HID))[t];
        float* dst = &tile[r][t * 8];
        dst[0] = lo_bf(raw.x); dst[1] = hi_bf(raw.x);
        dst[2] = lo_bf(raw.y); dst[3] = hi_bf(raw.y);
        dst[4] = lo_bf(raw.z); dst[5] = hi_bf(raw.z);
        dst[6] = lo_bf(raw.w); dst[7] = hi_bf(raw.w);
    }
    __syncthreads();
    float acc0[16], acc1[16];
#pragma unroll
    for (int r = 0; r < 16; r++) { acc0[r] = 0.f; acc1[r] = 0.f; }
    for (int k4 = 0; k4 < HID / 4; k4++) {
        int k = k4 * 4;
        float wa0 = mW0[(k + 0) * HID + lane], wb0 = mW0[(k + 0) * HID + lane + 64];
        float wa1 = mW0[(k + 1) * HID + lane], wb1 = mW0[(k + 1) * HID + lane + 64];
        float wa2 = mW0[(k + 2) * HID + lane], wb2 = mW0[(k + 2) * HID + lane + 64];
        float wa3 = mW0[(k + 3) * HID + lane], wb3 = mW0[(k + 3) * HID + lane + 64];
#pragma unroll
        for (int r = 0; r < 16; r++) {
            float4 h4 = *(const float4*)&tile[r][k];
            acc0[r] += h4.x * wa0 + h4.y * wa1 + h4.z * wa2 + h4.w * wa3;
            acc1[r] += h4.x * wb0 + h4.y * wb1 + h4.z * wb2 + h4.w * wb3;
        }
    }
    float w1a = mW1[lane], w1b = mW1[lane + 64];
    float b0a = mb0[lane], b0b = mb0[lane + 64];
    float bias1 = mb1[0];
#pragma unroll
    for (int r = 0; r < 16; r++) {
        float s = fmaxf(acc0[r] + b0a, 0.f) * w1a + fmaxf(acc1[r] + b0b, 0.f) * w1b;
#pragma unroll
        for (int off = 32; off > 0; off >>= 1) s += __shfl_down(s, off);
        if (lane == 0) sc[r] = s + bias1;
    }
    __syncthreads();
    if (lane == 0) {
        float m = -1e30f;
#pragma unroll
        for (int j = 0; j < 16; j++) m = fmaxf(m, sc[j]);
        float e[16], den = 0.f;
#pragma unroll
        for (int j = 0; j < 16; j++) { e[j] = __expf(sc[j] - m); den += e[j]; }
        float inv = 1.f / den;
#pragma unroll
        for (int j = 0; j < 16; j++) out[g * 16 + j] = e[j] * inv;
    }
}

// ---------------- launch ----------------

extern "C" void kernel_launch(void* const* d_in, const int* in_sizes, int n_in,
                              void* d_out, int out_size, void* d_ws, size_t ws_size,
                              hipStream_t stream) {
    const int N = N_NODES;
    const float* state = (const float*)d_in[0];
    const int* ei   = (const int*)d_in[1];
    const int* cand = (const int*)d_in[2];
    const float* W0  = (const float*)d_in[3];
    const float* as0 = (const float*)d_in[4];
    const float* ad0 = (const float*)d_in[5];
    const float* b0  = (const float*)d_in[6];
    const float* W1  = (const float*)d_in[7];
    const float* as1 = (const float*)d_in[8];
    const float* ad1 = (const float*)d_in[9];
    const float* b1  = (const float*)d_in[10];
    const float* mW0 = (const float*)d_in[11];
    const float* mb0 = (const float*)d_in[12];
    const float* mW1 = (const float*)d_in[13];
    const float* mb1 = (const float*)d_in[14];

    int E = in_sizes[1] / 2;
    int M = 2 * E;                    // symmetrized, self-loops inline in k_agg
    int indim = in_sizes[0] / N;
    int ncand = in_sizes[2];          // 65536
    int ngroups = ncand / 16;         // 4096

    // workspace (~59 MB); pairs overlays zb (dead until k_feat0)
    char* p = (char*)d_ws;
    bf16* zb = (bf16*)p;              p += (size_t)N * HID * 2;   // 25.6 MB
    bf16* hb = (bf16*)p;              p += (size_t)N * HID * 2;   // 25.6 MB
    float* es = (float*)p;            p += (size_t)N * 4;
    float* ed = (float*)p;            p += (size_t)N * 4;
    int* rowptr = (int*)p;            p += (size_t)(N + 1) * 4;
    int* col    = (int*)p;            p += (size_t)M * 4;         // 6.4 MB
    int* bcnt   = (int*)p;            p += (NBUCK + 1) * 4;
    int* bbase  = (int*)p;            p += (NBUCK + 1) * 4;
    int* bnext  = (int*)p;            p += NBUCK * 4;
    int2* pairs = (int2*)zb;          // 12.8 MB overlay

    int nwb = N / 4;                  // one-wave-per-node kernels, 256 thr

    // ---- CSR build (bucketed counting sort) ----
    k_zero_int<<<1, 256, 0, stream>>>(bcnt, NBUCK);
    k_bhist<<<512, 256, 0, stream>>>(ei, E, bcnt);
    k_bscan<<<1, NBUCK, 0, stream>>>(bcnt, bbase, bnext);
    k_bscatter<<<(E + SCH - 1) / SCH, 256, 0, stream>>>(ei, E, bnext, pairs);
    k_bbuild<<<NBUCK, 256, 0, stream>>>(pairs, bbase, rowptr, col, N);

    // ---- GAT layer 0 (es/ed fused into feature kernel) ----
    k_feat0<<<nwb, 256, 0, stream>>>(state, W0, as0, ad0, zb, es, ed, N, indim);
    k_agg<<<nwb, 256, 0, stream>>>(zb, rowptr, col, es, ed, b0, hb, N);

    // ---- GAT layer 1 ----
    k_feat1<<<N / 16, HID, 0, stream>>>(hb, W1, zb, N);
    k_attvec<<<nwb, 256, 0, stream>>>(zb, as1, ad1, es, ed, N);
    k_agg<<<nwb, 256, 0, stream>>>(zb, rowptr, col, es, ed, b1, hb, N);

    // ---- fused actor MLP + softmax (writes d_out directly) ----
    k_group<<<ngroups, 64, 0, stream>>>(hb, cand, mW0, mb0, mW1, mb1, (float*)d_out);
}